// Round 1
// baseline (646.406 us; speedup 1.0000x reference)
//
#include <hip/hip_runtime.h>
#include <hip/hip_bf16.h>

#define NB 4
#define CH 256
#define HWT 3600
#define KNN 8
#define ITERS 2
#define POSB 8

__device__ inline unsigned long long shfl_xor_u64(unsigned long long v, int mask) {
    int lo = __shfl_xor((int)(unsigned)(v & 0xffffffffULL), mask);
    int hi = __shfl_xor((int)(unsigned)(v >> 32), mask);
    return ((unsigned long long)(unsigned)hi << 32) | (unsigned)lo;
}

// one wave per row; rows = 2 (mod) * NB * HWT
__global__ __launch_bounds__(256) void knn_kernel(const float* __restrict__ rgb,
                                                  const float* __restrict__ ir,
                                                  int* __restrict__ knn_rgb,
                                                  int* __restrict__ knn_ir) {
    int wave = (blockIdx.x * blockDim.x + threadIdx.x) >> 6;
    int lane = threadIdx.x & 63;
    if (wave >= 2 * NB * HWT) return;
    int mod = wave / (NB * HWT);
    int rem = wave - mod * (NB * HWT);
    int n = rem / HWT;
    int i = rem - n * HWT;
    const float* x = (mod == 0 ? rgb : ir) + (size_t)n * 5 * HWT;
    float xi[5];
#pragma unroll
    for (int d = 0; d < 5; ++d) xi[d] = x[d * HWT + i];

    unsigned long long best[KNN];
#pragma unroll
    for (int r = 0; r < KNN; ++r) best[r] = ~0ULL;

    for (int j = lane; j < HWT; j += 64) {
        float d2 = 0.f;
#pragma unroll
        for (int d = 0; d < 5; ++d) {
            float t = xi[d] - x[d * HWT + j];
            d2 = fmaf(t, t, d2);
        }
        unsigned long long key =
            ((unsigned long long)__float_as_uint(d2) << 32) | (unsigned)j;
        if (key < best[KNN - 1]) {
            int p = KNN - 1;
            while (p > 0 && best[p - 1] > key) { best[p] = best[p - 1]; --p; }
            best[p] = key;
        }
    }
    // merge 64 lanes x sorted-8 -> global smallest 8 (ties -> lower idx, embedded in key)
    int ptr = 0;
    int* outp = (mod == 0 ? knn_rgb : knn_ir) + ((size_t)n * HWT + i) * KNN;
    for (int r = 0; r < KNN; ++r) {
        unsigned long long cand = (ptr < KNN) ? best[ptr] : ~0ULL;
        unsigned long long m = cand;
#pragma unroll
        for (int s = 32; s > 0; s >>= 1) {
            unsigned long long o = shfl_xor_u64(m, s);
            if (o < m) m = o;
        }
        if (cand == m) ++ptr;
        if (lane == 0) outp[r] = (int)(unsigned)(m & 0xffffffffu);
    }
}

// Wcomb [1024][256]: rows 0-255 (W1r+W2r), 256-511 (W2r), 512-767 (V1+V2), 768-1023 (V2)
// also init gate g = 1
__global__ void init_kernel(const float* __restrict__ Wg_rgb, const float* __restrict__ Wg_ir,
                            float* __restrict__ Wcomb, float* __restrict__ g) {
    int t = blockIdx.x * blockDim.x + threadIdx.x;
    if (t < 1024 * 256) {
        int o = t >> 8, j = t & 255;
        float v;
        if (o < 256)      v = Wg_rgb[o * 512 + j] + Wg_rgb[o * 512 + 256 + j];
        else if (o < 512) v = Wg_rgb[(o - 256) * 512 + 256 + j];
        else if (o < 768) v = Wg_ir[(o - 512) * 512 + j] + Wg_ir[(o - 512) * 512 + 256 + j];
        else              v = Wg_ir[(o - 768) * 512 + 256 + j];
        Wcomb[t] = v;
    }
    if (t < NB * CH) g[t] = 1.0f;
}

// Y[n][hw][o] (bf16) = sum_j g[n][j]*cnn[n][j][hw] * Wcomb[o][j]
// grid (57, 16, NB), block 256, 64x64 tile, 4x4 per thread
__global__ __launch_bounds__(256) void gemm_kernel(const float* __restrict__ cnn,
                                                   const float* __restrict__ Wcomb,
                                                   const float* __restrict__ g,
                                                   __hip_bfloat16* __restrict__ Yall) {
    __shared__ float As[16][64];
    __shared__ float Bs[16][68];  // padded: 16B-aligned rows, conflict-light writes
    int n = blockIdx.z;
    int hw0 = blockIdx.x * 64;
    int o0 = blockIdx.y * 64;
    const float* a = cnn + (size_t)n * CH * HWT;
    const float* gn = g + n * CH;
    int t = threadIdx.x;
    int tx = t & 15, ty = t >> 4;
    float acc[4][4] = {};

    for (int j0 = 0; j0 < CH; j0 += 16) {
#pragma unroll
        for (int r = 0; r < 4; ++r) {
            int e = t + r * 256;
            int j = e >> 6, hw = e & 63;
            int ghw = hw0 + hw;
            As[j][hw] = (ghw < HWT) ? gn[j0 + j] * a[(j0 + j) * HWT + ghw] : 0.f;
        }
#pragma unroll
        for (int r = 0; r < 4; ++r) {
            int e = t + r * 256;
            int o = e >> 4, j = e & 15;
            Bs[j][o] = Wcomb[(o0 + o) * 256 + j0 + j];
        }
        __syncthreads();
#pragma unroll
        for (int j = 0; j < 16; ++j) {
            float av[4], bv[4];
#pragma unroll
            for (int q = 0; q < 4; ++q) av[q] = As[j][ty * 4 + q];
#pragma unroll
            for (int q = 0; q < 4; ++q) bv[q] = Bs[j][tx * 4 + q];
#pragma unroll
            for (int p = 0; p < 4; ++p)
#pragma unroll
                for (int q = 0; q < 4; ++q) acc[p][q] = fmaf(av[p], bv[q], acc[p][q]);
        }
        __syncthreads();
    }
#pragma unroll
    for (int p = 0; p < 4; ++p) {
        int hw = hw0 + ty * 4 + p;
        if (hw < HWT) {
            __hip_bfloat16* yp = Yall + ((size_t)n * HWT + hw) * 1024 + o0 + tx * 4;
#pragma unroll
            for (int q = 0; q < 4; ++q) yp[q] = __float2bfloat16(acc[p][q]);
        }
    }
}

__global__ void zero_cc(float* __restrict__ ccsum) {
    int t = blockIdx.x * blockDim.x + threadIdx.x;
    if (t < NB * 512) ccsum[t] = 0.f;
}

// per position: m_rgb[c] = max_k relu(Ya_rgb[jr_k][c] - Yb_rgb[ji_k][c] + br)
//               m_ir [c] = max_k relu(Ya_ir [ji_k][c] - Yb_ir [jr_k][c] + bi)
// accumulate sums over hw into ccsum[n][0:256]=rgb, [256:512]=ir
__global__ __launch_bounds__(256) void gather_kernel(const __hip_bfloat16* __restrict__ Yall,
                                                     const int* __restrict__ knn_rgb,
                                                     const int* __restrict__ knn_ir,
                                                     const float* __restrict__ b_rgb,
                                                     const float* __restrict__ b_ir,
                                                     float* __restrict__ ccsum) {
    int n = blockIdx.y;
    int hwbase = blockIdx.x * POSB;
    int c = threadIdx.x;
    __shared__ int sidx[POSB][2][KNN];
    if (c < POSB * 2 * KNN) {
        int p = c >> 4, rem = c & 15;
        int hw = hwbase + p;
        int v;
        if (rem < 8) v = knn_rgb[((size_t)n * HWT + hw) * KNN + rem];
        else         v = knn_ir[((size_t)n * HWT + hw) * KNN + (rem - 8)];
        sidx[p][rem >> 3][rem & 7] = v;
    }
    __syncthreads();
    float br = b_rgb[c], bi = b_ir[c];
    float acc_r = 0.f, acc_i = 0.f;
    const __hip_bfloat16* Y = Yall + (size_t)n * HWT * 1024;
    for (int p = 0; p < POSB; ++p) {
        float mr = 0.f, mi = 0.f;  // relu floor
#pragma unroll
        for (int k = 0; k < KNN; ++k) {
            int jr = sidx[p][0][k];
            int ji = sidx[p][1][k];
            float y1 = __bfloat162float(Y[(size_t)jr * 1024 + c]);
            float y2 = __bfloat162float(Y[(size_t)ji * 1024 + 256 + c]);
            mr = fmaxf(mr, y1 - y2 + br);
            float z1 = __bfloat162float(Y[(size_t)ji * 1024 + 512 + c]);
            float z2 = __bfloat162float(Y[(size_t)jr * 1024 + 768 + c]);
            mi = fmaxf(mi, z1 - z2 + bi);
        }
        acc_r += mr;
        acc_i += mi;
    }
    atomicAdd(&ccsum[n * 512 + c], acc_r);
    atomicAdd(&ccsum[n * 512 + 256 + c], acc_i);
}

// SE MLP per batch; multiply gate into g
__global__ __launch_bounds__(256) void se_kernel(const float* __restrict__ ccsum,
                                                 const float* __restrict__ W1,
                                                 const float* __restrict__ b1,
                                                 const float* __restrict__ W2,
                                                 const float* __restrict__ b2,
                                                 float* __restrict__ g) {
    int n = blockIdx.x;
    int t = threadIdx.x;
    __shared__ float hid[16];
    __shared__ float cc[512];
    cc[t] = ccsum[n * 512 + t] * (1.0f / HWT);
    cc[256 + t] = ccsum[n * 512 + 256 + t] * (1.0f / HWT);
    __syncthreads();
    if (t < 16) {
        float s = b1[t];
        for (int j = 0; j < 512; ++j) s = fmaf(W1[t * 512 + j], cc[j], s);
        hid[t] = fmaxf(s, 0.f);
    }
    __syncthreads();
    float s = b2[t];
#pragma unroll
    for (int q = 0; q < 16; ++q) s = fmaf(W2[t * 16 + q], hid[q], s);
    float se = 1.0f / (1.0f + expf(-s));
    g[n * CH + t] *= se;
}

// out = relu((gamma*g[n,c] + 1) * x)
__global__ void final_kernel(const float* __restrict__ cnn, const float* __restrict__ g,
                             const float* __restrict__ gamma, float* __restrict__ out) {
    int t = blockIdx.x * blockDim.x + threadIdx.x;
    if (t >= NB * CH * HWT) return;
    int nc = t / HWT;
    float x = cnn[t];
    float s = gamma[0] * g[nc] + 1.0f;
    out[t] = fmaxf(s * x, 0.f);
}

extern "C" void kernel_launch(void* const* d_in, const int* in_sizes, int n_in,
                              void* d_out, int out_size, void* d_ws, size_t ws_size,
                              hipStream_t stream) {
    const float* cnn    = (const float*)d_in[0];
    const float* rgb    = (const float*)d_in[1];
    const float* ir     = (const float*)d_in[2];
    const float* Wg_rgb = (const float*)d_in[3];
    const float* bg_rgb = (const float*)d_in[4];
    const float* Wg_ir  = (const float*)d_in[5];
    const float* bg_ir  = (const float*)d_in[6];
    const float* Wse1   = (const float*)d_in[7];
    const float* bse1   = (const float*)d_in[8];
    const float* Wse2   = (const float*)d_in[9];
    const float* bse2   = (const float*)d_in[10];
    const float* gamma  = (const float*)d_in[11];
    float* out = (float*)d_out;

    char* ws = (char*)d_ws;
    size_t off = 0;
    int* knn_rgb = (int*)(ws + off); off += (size_t)NB * HWT * KNN * 4;        // 460800
    int* knn_ir  = (int*)(ws + off); off += (size_t)NB * HWT * KNN * 4;        // 460800
    float* Wcomb = (float*)(ws + off); off += (size_t)1024 * 256 * 4;          // 1 MB
    __hip_bfloat16* Yall = (__hip_bfloat16*)(ws + off);
    off += (size_t)NB * HWT * 1024 * 2;                                        // 29.5 MB
    float* ccsum = (float*)(ws + off); off += (size_t)NB * 512 * 4;
    float* g     = (float*)(ws + off); off += (size_t)NB * CH * 4;
    // total ~31.5 MB (assumed <= ws_size)

    knn_kernel<<<7200, 256, 0, stream>>>(rgb, ir, knn_rgb, knn_ir);
    init_kernel<<<1024, 256, 0, stream>>>(Wg_rgb, Wg_ir, Wcomb, g);

    for (int it = 0; it < ITERS; ++it) {
        gemm_kernel<<<dim3(57, 16, NB), 256, 0, stream>>>(cnn, Wcomb, g, Yall);
        zero_cc<<<8, 256, 0, stream>>>(ccsum);
        gather_kernel<<<dim3(HWT / POSB, NB), 256, 0, stream>>>(Yall, knn_rgb, knn_ir,
                                                                bg_rgb, bg_ir, ccsum);
        se_kernel<<<NB, 256, 0, stream>>>(ccsum, Wse1, bse1, Wse2, bse2, g);
    }
    final_kernel<<<(NB * CH * HWT + 255) / 256, 256, 0, stream>>>(cnn, g, gamma, out);
}

// Round 2
// 430.937 us; speedup vs baseline: 1.5000x; 1.5000x over previous
//
#include <hip/hip_runtime.h>
#include <hip/hip_bf16.h>

#define NB 4
#define CH 256
#define HWT 3600
#define KNN 8
#define ITERS 2
#define POSB 8

#define S_SEG 15   // j-segments per row
#define TILE 60    // j per LDS tile
#define TPS 4      // tiles per segment (S_SEG*TPS*TILE == HWT)
#define RPT 4      // rows per thread

__device__ inline float med3f(float a, float b, float c) {
    return __builtin_amdgcn_fmed3f(a, b, c);
}

// xpack[nm][j][8] = {x0..x4, q=|x|^2, 0, 0}; nm = mod*NB + n
__global__ void knn_prep(const float* __restrict__ rgb, const float* __restrict__ ir,
                         float* __restrict__ xpack) {
    int t = blockIdx.x * blockDim.x + threadIdx.x;
    if (t >= 2 * NB * HWT) return;
    int nm = t / HWT, j = t - nm * HWT;
    int mod = nm / NB, n = nm - mod * NB;
    const float* x = (mod == 0 ? rgb : ir) + (size_t)n * 5 * HWT;
    float v[5], q = 0.f;
#pragma unroll
    for (int d = 0; d < 5; ++d) { v[d] = x[d * HWT + j]; q = fmaf(v[d], v[d], q); }
    float* o = xpack + (size_t)t * 8;
#pragma unroll
    for (int d = 0; d < 5; ++d) o[d] = v[d];
    o[5] = q; o[6] = 0.f; o[7] = 0.f;
}

// branchless top-8 via med3 sorted-insert; key = (bits(d2+1) & ~0xFFF) | j
// partial[(nm*S_SEG + seg)*HWT + row][8]
__global__ __launch_bounds__(256) void knn_main(const float* __restrict__ xpack,
                                                unsigned* __restrict__ partial) {
    int seg = blockIdx.x, rb = blockIdx.y, nm = blockIdx.z;
    int t = threadIdx.x;
    int row0 = rb * 1024 + t * RPT;
    const float* xp = xpack + (size_t)nm * HWT * 8;
    __shared__ float4 xs[TILE * 2];

    float xi[RPT][5], qi1[RPT];
#pragma unroll
    for (int r = 0; r < RPT; ++r) {
        int row = row0 + r;
        int rr = (row < HWT) ? row : (HWT - 1);
        float4 a = ((const float4*)xp)[rr * 2];
        float4 b = ((const float4*)xp)[rr * 2 + 1];
        xi[r][0] = a.x; xi[r][1] = a.y; xi[r][2] = a.z; xi[r][3] = a.w; xi[r][4] = b.x;
        qi1[r] = b.y + 1.0f;
    }
    const float BIG = __uint_as_float(0x7F000000u);
    float best[RPT][8];
#pragma unroll
    for (int r = 0; r < RPT; ++r)
#pragma unroll
        for (int i = 0; i < 8; ++i) best[r][i] = BIG;

    int jbase = seg * (TPS * TILE);
    for (int tl = 0; tl < TPS; ++tl) {
        int j0 = jbase + tl * TILE;
        __syncthreads();
        if (t < TILE * 2) xs[t] = ((const float4*)xp)[j0 * 2 + t];
        __syncthreads();
        for (int jj = 0; jj < TILE; ++jj) {
            float4 a = xs[jj * 2];
            float4 b = xs[jj * 2 + 1];
            unsigned jg = (unsigned)(j0 + jj);
#pragma unroll
            for (int r = 0; r < RPT; ++r) {
                float dot = a.x * xi[r][0];
                dot = fmaf(a.y, xi[r][1], dot);
                dot = fmaf(a.z, xi[r][2], dot);
                dot = fmaf(a.w, xi[r][3], dot);
                dot = fmaf(b.x, xi[r][4], dot);
                float d2 = fmaf(-2.0f, dot, b.y + qi1[r]);  // d^2 + 1, >= ~1
                unsigned kb = (__float_as_uint(d2) & 0xFFFFF000u) | jg;
                float kf = __uint_as_float(kb);
                best[r][7] = med3f(best[r][6], best[r][7], kf);
                best[r][6] = med3f(best[r][5], best[r][6], kf);
                best[r][5] = med3f(best[r][4], best[r][5], kf);
                best[r][4] = med3f(best[r][3], best[r][4], kf);
                best[r][3] = med3f(best[r][2], best[r][3], kf);
                best[r][2] = med3f(best[r][1], best[r][2], kf);
                best[r][1] = med3f(best[r][0], best[r][1], kf);
                best[r][0] = fminf(best[r][0], kf);
            }
        }
    }
#pragma unroll
    for (int r = 0; r < RPT; ++r) {
        int row = row0 + r;
        if (row < HWT) {
            unsigned* o = partial + (((size_t)nm * S_SEG + seg) * HWT + row) * 8;
            uint4 lo = { __float_as_uint(best[r][0]), __float_as_uint(best[r][1]),
                         __float_as_uint(best[r][2]), __float_as_uint(best[r][3]) };
            uint4 hi = { __float_as_uint(best[r][4]), __float_as_uint(best[r][5]),
                         __float_as_uint(best[r][6]), __float_as_uint(best[r][7]) };
            ((uint4*)o)[0] = lo;
            ((uint4*)o)[1] = hi;
        }
    }
}

__global__ void knn_merge(const unsigned* __restrict__ partial,
                          int* __restrict__ knn_rgb, int* __restrict__ knn_ir) {
    int t = blockIdx.x * blockDim.x + threadIdx.x;
    if (t >= 2 * NB * HWT) return;
    int nm = t / HWT, row = t - nm * HWT;
    const float BIG = __uint_as_float(0x7F000000u);
    float best[8];
#pragma unroll
    for (int i = 0; i < 8; ++i) best[i] = BIG;
    for (int s = 0; s < S_SEG; ++s) {
        const unsigned* p = partial + (((size_t)nm * S_SEG + s) * HWT + row) * 8;
#pragma unroll
        for (int w = 0; w < 2; ++w) {
            uint4 v = ((const uint4*)p)[w];
            unsigned vv[4] = { v.x, v.y, v.z, v.w };
#pragma unroll
            for (int e = 0; e < 4; ++e) {
                float kf = __uint_as_float(vv[e]);
                best[7] = med3f(best[6], best[7], kf);
                best[6] = med3f(best[5], best[6], kf);
                best[5] = med3f(best[4], best[5], kf);
                best[4] = med3f(best[3], best[4], kf);
                best[3] = med3f(best[2], best[3], kf);
                best[2] = med3f(best[1], best[2], kf);
                best[1] = med3f(best[0], best[1], kf);
                best[0] = fminf(best[0], kf);
            }
        }
    }
    int mod = nm / NB, n = nm - mod * NB;
    int* o = (mod == 0 ? knn_rgb : knn_ir) + ((size_t)n * HWT + row) * KNN;
#pragma unroll
    for (int i = 0; i < 8; ++i) o[i] = (int)(__float_as_uint(best[i]) & 0xFFFu);
}

// Wcomb [1024][256]: rows 0-255 (W1r+W2r), 256-511 (W2r), 512-767 (V1+V2), 768-1023 (V2)
__global__ void init_kernel(const float* __restrict__ Wg_rgb, const float* __restrict__ Wg_ir,
                            float* __restrict__ Wcomb, float* __restrict__ g) {
    int t = blockIdx.x * blockDim.x + threadIdx.x;
    if (t < 1024 * 256) {
        int o = t >> 8, j = t & 255;
        float v;
        if (o < 256)      v = Wg_rgb[o * 512 + j] + Wg_rgb[o * 512 + 256 + j];
        else if (o < 512) v = Wg_rgb[(o - 256) * 512 + 256 + j];
        else if (o < 768) v = Wg_ir[(o - 512) * 512 + j] + Wg_ir[(o - 512) * 512 + 256 + j];
        else              v = Wg_ir[(o - 768) * 512 + 256 + j];
        Wcomb[t] = v;
    }
    if (t < NB * CH) g[t] = 1.0f;
}

// Y[n][hw][o] (bf16) = sum_j g[n][j]*cnn[n][j][hw] * Wcomb[o][j]
__global__ __launch_bounds__(256) void gemm_kernel(const float* __restrict__ cnn,
                                                   const float* __restrict__ Wcomb,
                                                   const float* __restrict__ g,
                                                   __hip_bfloat16* __restrict__ Yall) {
    __shared__ float As[16][64];
    __shared__ float Bs[16][68];
    int n = blockIdx.z;
    int hw0 = blockIdx.x * 64;
    int o0 = blockIdx.y * 64;
    const float* a = cnn + (size_t)n * CH * HWT;
    const float* gn = g + n * CH;
    int t = threadIdx.x;
    int tx = t & 15, ty = t >> 4;
    float acc[4][4] = {};

    for (int j0 = 0; j0 < CH; j0 += 16) {
#pragma unroll
        for (int r = 0; r < 4; ++r) {
            int e = t + r * 256;
            int j = e >> 6, hw = e & 63;
            int ghw = hw0 + hw;
            As[j][hw] = (ghw < HWT) ? gn[j0 + j] * a[(j0 + j) * HWT + ghw] : 0.f;
        }
#pragma unroll
        for (int r = 0; r < 4; ++r) {
            int e = t + r * 256;
            int o = e >> 4, j = e & 15;
            Bs[j][o] = Wcomb[(o0 + o) * 256 + j0 + j];
        }
        __syncthreads();
#pragma unroll
        for (int j = 0; j < 16; ++j) {
            float av[4], bv[4];
#pragma unroll
            for (int q = 0; q < 4; ++q) av[q] = As[j][ty * 4 + q];
#pragma unroll
            for (int q = 0; q < 4; ++q) bv[q] = Bs[j][tx * 4 + q];
#pragma unroll
            for (int p = 0; p < 4; ++p)
#pragma unroll
                for (int q = 0; q < 4; ++q) acc[p][q] = fmaf(av[p], bv[q], acc[p][q]);
        }
        __syncthreads();
    }
#pragma unroll
    for (int p = 0; p < 4; ++p) {
        int hw = hw0 + ty * 4 + p;
        if (hw < HWT) {
            __hip_bfloat16* yp = Yall + ((size_t)n * HWT + hw) * 1024 + o0 + tx * 4;
#pragma unroll
            for (int q = 0; q < 4; ++q) yp[q] = __float2bfloat16(acc[p][q]);
        }
    }
}

__global__ void zero_cc(float* __restrict__ ccsum) {
    int t = blockIdx.x * blockDim.x + threadIdx.x;
    if (t < NB * 512) ccsum[t] = 0.f;
}

__global__ __launch_bounds__(256) void gather_kernel(const __hip_bfloat16* __restrict__ Yall,
                                                     const int* __restrict__ knn_rgb,
                                                     const int* __restrict__ knn_ir,
                                                     const float* __restrict__ b_rgb,
                                                     const float* __restrict__ b_ir,
                                                     float* __restrict__ ccsum) {
    int n = blockIdx.y;
    int hwbase = blockIdx.x * POSB;
    int c = threadIdx.x;
    __shared__ int sidx[POSB][2][KNN];
    if (c < POSB * 2 * KNN) {
        int p = c >> 4, rem = c & 15;
        int hw = hwbase + p;
        int v;
        if (rem < 8) v = knn_rgb[((size_t)n * HWT + hw) * KNN + rem];
        else         v = knn_ir[((size_t)n * HWT + hw) * KNN + (rem - 8)];
        sidx[p][rem >> 3][rem & 7] = v;
    }
    __syncthreads();
    float br = b_rgb[c], bi = b_ir[c];
    float acc_r = 0.f, acc_i = 0.f;
    const __hip_bfloat16* Y = Yall + (size_t)n * HWT * 1024;
    for (int p = 0; p < POSB; ++p) {
        float mr = 0.f, mi = 0.f;
#pragma unroll
        for (int k = 0; k < KNN; ++k) {
            int jr = sidx[p][0][k];
            int ji = sidx[p][1][k];
            float y1 = __bfloat162float(Y[(size_t)jr * 1024 + c]);
            float y2 = __bfloat162float(Y[(size_t)ji * 1024 + 256 + c]);
            mr = fmaxf(mr, y1 - y2 + br);
            float z1 = __bfloat162float(Y[(size_t)ji * 1024 + 512 + c]);
            float z2 = __bfloat162float(Y[(size_t)jr * 1024 + 768 + c]);
            mi = fmaxf(mi, z1 - z2 + bi);
        }
        acc_r += mr;
        acc_i += mi;
    }
    atomicAdd(&ccsum[n * 512 + c], acc_r);
    atomicAdd(&ccsum[n * 512 + 256 + c], acc_i);
}

__global__ __launch_bounds__(256) void se_kernel(const float* __restrict__ ccsum,
                                                 const float* __restrict__ W1,
                                                 const float* __restrict__ b1,
                                                 const float* __restrict__ W2,
                                                 const float* __restrict__ b2,
                                                 float* __restrict__ g) {
    int n = blockIdx.x;
    int t = threadIdx.x;
    __shared__ float hid[16];
    __shared__ float cc[512];
    cc[t] = ccsum[n * 512 + t] * (1.0f / HWT);
    cc[256 + t] = ccsum[n * 512 + 256 + t] * (1.0f / HWT);
    __syncthreads();
    if (t < 16) {
        float s = b1[t];
        for (int j = 0; j < 512; ++j) s = fmaf(W1[t * 512 + j], cc[j], s);
        hid[t] = fmaxf(s, 0.f);
    }
    __syncthreads();
    float s = b2[t];
#pragma unroll
    for (int q = 0; q < 16; ++q) s = fmaf(W2[t * 16 + q], hid[q], s);
    float se = 1.0f / (1.0f + expf(-s));
    g[n * CH + t] *= se;
}

__global__ void final_kernel(const float* __restrict__ cnn, const float* __restrict__ g,
                             const float* __restrict__ gamma, float* __restrict__ out) {
    int t = blockIdx.x * blockDim.x + threadIdx.x;
    if (t >= NB * CH * HWT) return;
    int nc = t / HWT;
    float x = cnn[t];
    float s = gamma[0] * g[nc] + 1.0f;
    out[t] = fmaxf(s * x, 0.f);
}

extern "C" void kernel_launch(void* const* d_in, const int* in_sizes, int n_in,
                              void* d_out, int out_size, void* d_ws, size_t ws_size,
                              hipStream_t stream) {
    const float* cnn    = (const float*)d_in[0];
    const float* rgb    = (const float*)d_in[1];
    const float* ir     = (const float*)d_in[2];
    const float* Wg_rgb = (const float*)d_in[3];
    const float* bg_rgb = (const float*)d_in[4];
    const float* Wg_ir  = (const float*)d_in[5];
    const float* bg_ir  = (const float*)d_in[6];
    const float* Wse1   = (const float*)d_in[7];
    const float* bse1   = (const float*)d_in[8];
    const float* Wse2   = (const float*)d_in[9];
    const float* bse2   = (const float*)d_in[10];
    const float* gamma  = (const float*)d_in[11];
    float* out = (float*)d_out;

    char* ws = (char*)d_ws;
    size_t off = 0;
    float* xpack = (float*)(ws + off); off += (size_t)2 * NB * HWT * 8 * 4;    // 921.6 KB
    int* knn_rgb = (int*)(ws + off); off += (size_t)NB * HWT * KNN * 4;
    int* knn_ir  = (int*)(ws + off); off += (size_t)NB * HWT * KNN * 4;
    float* Wcomb = (float*)(ws + off); off += (size_t)1024 * 256 * 4;
    __hip_bfloat16* Yall = (__hip_bfloat16*)(ws + off);
    unsigned* partial = (unsigned*)Yall;  // aliases Y: dead before first gemm
    off += (size_t)NB * HWT * 1024 * 2;                                        // 29.5 MB
    float* ccsum = (float*)(ws + off); off += (size_t)NB * 512 * 4;
    float* g     = (float*)(ws + off); off += (size_t)NB * CH * 4;

    knn_prep<<<(2 * NB * HWT + 255) / 256, 256, 0, stream>>>(rgb, ir, xpack);
    knn_main<<<dim3(S_SEG, 4, 2 * NB), 256, 0, stream>>>(xpack, partial);
    knn_merge<<<(2 * NB * HWT + 255) / 256, 256, 0, stream>>>(partial, knn_rgb, knn_ir);
    init_kernel<<<1024, 256, 0, stream>>>(Wg_rgb, Wg_ir, Wcomb, g);

    for (int it = 0; it < ITERS; ++it) {
        gemm_kernel<<<dim3(57, 16, NB), 256, 0, stream>>>(cnn, Wcomb, g, Yall);
        zero_cc<<<8, 256, 0, stream>>>(ccsum);
        gather_kernel<<<dim3(HWT / POSB, NB), 256, 0, stream>>>(Yall, knn_rgb, knn_ir,
                                                                bg_rgb, bg_ir, ccsum);
        se_kernel<<<NB, 256, 0, stream>>>(ccsum, Wse1, bse1, Wse2, bse2, g);
    }
    final_kernel<<<(NB * CH * HWT + 255) / 256, 256, 0, stream>>>(cnn, g, gamma, out);
}

// Round 3
// 329.364 us; speedup vs baseline: 1.9626x; 1.3084x over previous
//
#include <hip/hip_runtime.h>
#include <hip/hip_bf16.h>

#define NB 4
#define CH 256
#define HWT 3600
#define KNN 8
#define ITERS 2
#define POSB 8
#define MPAD 3712

#define S_SEG 15
#define TILE 60
#define TPS 4
#define RPT 4

typedef __attribute__((ext_vector_type(8))) __bf16 bf16x8;
typedef __attribute__((ext_vector_type(4))) float f32x4;

__device__ inline float med3f(float a, float b, float c) {
    return __builtin_amdgcn_fmed3f(a, b, c);
}

// ---------------- kNN (unchanged from round 2) ----------------
__global__ void knn_prep(const float* __restrict__ rgb, const float* __restrict__ ir,
                         float* __restrict__ xpack) {
    int t = blockIdx.x * blockDim.x + threadIdx.x;
    if (t >= 2 * NB * HWT) return;
    int nm = t / HWT, j = t - nm * HWT;
    int mod = nm / NB, n = nm - mod * NB;
    const float* x = (mod == 0 ? rgb : ir) + (size_t)n * 5 * HWT;
    float v[5], q = 0.f;
#pragma unroll
    for (int d = 0; d < 5; ++d) { v[d] = x[d * HWT + j]; q = fmaf(v[d], v[d], q); }
    float* o = xpack + (size_t)t * 8;
#pragma unroll
    for (int d = 0; d < 5; ++d) o[d] = v[d];
    o[5] = q; o[6] = 0.f; o[7] = 0.f;
}

__global__ __launch_bounds__(256) void knn_main(const float* __restrict__ xpack,
                                                unsigned* __restrict__ partial) {
    int seg = blockIdx.x, rb = blockIdx.y, nm = blockIdx.z;
    int t = threadIdx.x;
    int row0 = rb * 1024 + t * RPT;
    const float* xp = xpack + (size_t)nm * HWT * 8;
    __shared__ float4 xs[TILE * 2];

    float xi[RPT][5], qi1[RPT];
#pragma unroll
    for (int r = 0; r < RPT; ++r) {
        int row = row0 + r;
        int rr = (row < HWT) ? row : (HWT - 1);
        float4 a = ((const float4*)xp)[rr * 2];
        float4 b = ((const float4*)xp)[rr * 2 + 1];
        xi[r][0] = a.x; xi[r][1] = a.y; xi[r][2] = a.z; xi[r][3] = a.w; xi[r][4] = b.x;
        qi1[r] = b.y + 1.0f;
    }
    const float BIG = __uint_as_float(0x7F000000u);
    float best[RPT][8];
#pragma unroll
    for (int r = 0; r < RPT; ++r)
#pragma unroll
        for (int i = 0; i < 8; ++i) best[r][i] = BIG;

    int jbase = seg * (TPS * TILE);
    for (int tl = 0; tl < TPS; ++tl) {
        int j0 = jbase + tl * TILE;
        __syncthreads();
        if (t < TILE * 2) xs[t] = ((const float4*)xp)[j0 * 2 + t];
        __syncthreads();
        for (int jj = 0; jj < TILE; ++jj) {
            float4 a = xs[jj * 2];
            float4 b = xs[jj * 2 + 1];
            unsigned jg = (unsigned)(j0 + jj);
#pragma unroll
            for (int r = 0; r < RPT; ++r) {
                float dot = a.x * xi[r][0];
                dot = fmaf(a.y, xi[r][1], dot);
                dot = fmaf(a.z, xi[r][2], dot);
                dot = fmaf(a.w, xi[r][3], dot);
                dot = fmaf(b.x, xi[r][4], dot);
                float d2 = fmaf(-2.0f, dot, b.y + qi1[r]);
                unsigned kb = (__float_as_uint(d2) & 0xFFFFF000u) | jg;
                float kf = __uint_as_float(kb);
                best[r][7] = med3f(best[r][6], best[r][7], kf);
                best[r][6] = med3f(best[r][5], best[r][6], kf);
                best[r][5] = med3f(best[r][4], best[r][5], kf);
                best[r][4] = med3f(best[r][3], best[r][4], kf);
                best[r][3] = med3f(best[r][2], best[r][3], kf);
                best[r][2] = med3f(best[r][1], best[r][2], kf);
                best[r][1] = med3f(best[r][0], best[r][1], kf);
                best[r][0] = fminf(best[r][0], kf);
            }
        }
    }
#pragma unroll
    for (int r = 0; r < RPT; ++r) {
        int row = row0 + r;
        if (row < HWT) {
            unsigned* o = partial + (((size_t)nm * S_SEG + seg) * HWT + row) * 8;
            uint4 lo = { __float_as_uint(best[r][0]), __float_as_uint(best[r][1]),
                         __float_as_uint(best[r][2]), __float_as_uint(best[r][3]) };
            uint4 hi = { __float_as_uint(best[r][4]), __float_as_uint(best[r][5]),
                         __float_as_uint(best[r][6]), __float_as_uint(best[r][7]) };
            ((uint4*)o)[0] = lo;
            ((uint4*)o)[1] = hi;
        }
    }
}

__global__ void knn_merge(const unsigned* __restrict__ partial,
                          int* __restrict__ knn_rgb, int* __restrict__ knn_ir) {
    int t = blockIdx.x * blockDim.x + threadIdx.x;
    if (t >= 2 * NB * HWT) return;
    int nm = t / HWT, row = t - nm * HWT;
    const float BIG = __uint_as_float(0x7F000000u);
    float best[8];
#pragma unroll
    for (int i = 0; i < 8; ++i) best[i] = BIG;
    for (int s = 0; s < S_SEG; ++s) {
        const unsigned* p = partial + (((size_t)nm * S_SEG + s) * HWT + row) * 8;
#pragma unroll
        for (int w = 0; w < 2; ++w) {
            uint4 v = ((const uint4*)p)[w];
            unsigned vv[4] = { v.x, v.y, v.z, v.w };
#pragma unroll
            for (int e = 0; e < 4; ++e) {
                float kf = __uint_as_float(vv[e]);
                best[7] = med3f(best[6], best[7], kf);
                best[6] = med3f(best[5], best[6], kf);
                best[5] = med3f(best[4], best[5], kf);
                best[4] = med3f(best[3], best[4], kf);
                best[3] = med3f(best[2], best[3], kf);
                best[2] = med3f(best[1], best[2], kf);
                best[1] = med3f(best[0], best[1], kf);
                best[0] = fminf(best[0], kf);
            }
        }
    }
    int mod = nm / NB, n = nm - mod * NB;
    int* o = (mod == 0 ? knn_rgb : knn_ir) + ((size_t)n * HWT + row) * KNN;
#pragma unroll
    for (int i = 0; i < 8; ++i) o[i] = (int)(__float_as_uint(best[i]) & 0xFFFu);
}

// ---------------- weight prep ----------------
// Wcomb [1024][256] fp32: rows 0-255 (W1r+W2r), 256-511 (W2r), 512-767 (V1+V2), 768-1023 (V2)
__global__ void init_kernel(const float* __restrict__ Wg_rgb, const float* __restrict__ Wg_ir,
                            float* __restrict__ Wcomb, float* __restrict__ g) {
    int t = blockIdx.x * blockDim.x + threadIdx.x;
    if (t < 1024 * 256) {
        int o = t >> 8, j = t & 255;
        float v;
        if (o < 256)      v = Wg_rgb[o * 512 + j] + Wg_rgb[o * 512 + 256 + j];
        else if (o < 512) v = Wg_rgb[(o - 256) * 512 + 256 + j];
        else if (o < 768) v = Wg_ir[(o - 512) * 512 + j] + Wg_ir[(o - 512) * 512 + 256 + j];
        else              v = Wg_ir[(o - 768) * 512 + 256 + j];
        Wcomb[t] = v;
    }
    if (t < NB * CH) g[t] = 1.0f;
}

// Wbf[n][o][k] = bf16(Wcomb[o][k] * g[n][k])
__global__ __launch_bounds__(256) void scale_w(const float* __restrict__ Wcomb,
                                               const float* __restrict__ g,
                                               __hip_bfloat16* __restrict__ Wbf) {
    int n = blockIdx.y;
    int gid = blockIdx.x * 256 + threadIdx.x;   // 32768 total
    int o = gid >> 5;
    int kb = (gid & 31) * 8;
    const float* w = Wcomb + o * 256 + kb;
    const float* gp = g + n * CH + kb;
    union { uint4 u; __hip_bfloat16 h[8]; } pk;
#pragma unroll
    for (int i = 0; i < 8; ++i) pk.h[i] = __float2bfloat16(w[i] * gp[i]);
    *(uint4*)(Wbf + ((size_t)n * 1024 + o) * CH + kb) = pk.u;
}

// Abf[n][m][k] = bf16(cnn[n][k][m]), m padded to MPAD with zeros
__global__ __launch_bounds__(256) void convert_a(const float* __restrict__ cnn,
                                                 __hip_bfloat16* __restrict__ Abf) {
    __shared__ float st[64][65];
    int n = blockIdx.z, k0 = blockIdx.y * 64, m0 = blockIdx.x * 64;
    int t = threadIdx.x;
    const float* src = cnn + (size_t)n * CH * HWT;
#pragma unroll
    for (int r = 0; r < 4; ++r) {
        int kl = r * 16 + (t >> 4);
        int ms = (t & 15) * 4;
        float4 v = {0.f, 0.f, 0.f, 0.f};
        if (m0 + ms < HWT) v = *(const float4*)(src + (size_t)(k0 + kl) * HWT + m0 + ms);
        st[ms + 0][kl] = v.x; st[ms + 1][kl] = v.y;
        st[ms + 2][kl] = v.z; st[ms + 3][kl] = v.w;
    }
    __syncthreads();
    int m = t >> 2, kg = (t & 3) * 16;
    union { uint4 u[2]; __hip_bfloat16 h[16]; } pk;
#pragma unroll
    for (int i = 0; i < 16; ++i) pk.h[i] = __float2bfloat16(st[m][kg + i]);
    __hip_bfloat16* dst = Abf + ((size_t)n * MPAD + m0 + m) * CH + k0 + kg;
    ((uint4*)dst)[0] = pk.u[0];
    ((uint4*)dst)[1] = pk.u[1];
}

// ---------------- MFMA GEMM: Y[n][m][o] = sum_k Abf[n][m][k] * Wbf[n][o][k] ----------------
// 128x128 tile, 4 waves (2x2, each 64x64), K_STEP=64, XOR-swizzled LDS
__global__ __launch_bounds__(256) void gemm_mfma(const __hip_bfloat16* __restrict__ Abf,
                                                 const __hip_bfloat16* __restrict__ Wbf,
                                                 __hip_bfloat16* __restrict__ Yall) {
    __shared__ char sA[16384];   // H tile [128 m][64 k] bf16, slot-swizzled
    __shared__ char sB[16384];   // W tile [128 o][64 k]
    int n = blockIdx.z;
    int m0 = blockIdx.x * 128;
    int o0 = blockIdx.y * 128;
    int t = threadIdx.x;
    int lane = t & 63, wid = t >> 6;
    int wm = wid >> 1, wo = wid & 1;

    const __hip_bfloat16* Ab = Abf + (size_t)n * MPAD * CH;
    const __hip_bfloat16* Wb = Wbf + (size_t)n * 1024 * CH;

    f32x4 acc[4][4] = {};

    int srow = t >> 3;            // 0..31 (+32 per r)
    int sslot = t & 7;
    int swz = (sslot ^ (srow & 7)) << 4;   // (srow+32r)&7 == srow&7
    int fr = lane & 15;
    int kg = lane >> 4;
    int p = lane & 7;

    for (int ks = 0; ks < 4; ++ks) {
        uint4 av[4], bv[4];
#pragma unroll
        for (int r = 0; r < 4; ++r) {
            int row = srow + 32 * r;
            av[r] = *(const uint4*)(Ab + ((size_t)(m0 + row)) * CH + ks * 64 + sslot * 8);
            bv[r] = *(const uint4*)(Wb + ((size_t)(o0 + row)) * CH + ks * 64 + sslot * 8);
        }
        __syncthreads();   // all waves done reading previous tile
#pragma unroll
        for (int r = 0; r < 4; ++r) {
            int row = srow + 32 * r;
            *(uint4*)(sA + row * 128 + swz) = av[r];
            *(uint4*)(sB + row * 128 + swz) = bv[r];
        }
        __syncthreads();
#pragma unroll
        for (int kk = 0; kk < 2; ++kk) {
            bf16x8 hf[4], wf[4];
            int slot = kk * 4 + kg;
            int inrow = (slot ^ p) << 4;
#pragma unroll
            for (int f = 0; f < 4; ++f) {
                hf[f] = *(const bf16x8*)(sA + (wm * 64 + f * 16 + fr) * 128 + inrow);
                wf[f] = *(const bf16x8*)(sB + (wo * 64 + f * 16 + fr) * 128 + inrow);
            }
#pragma unroll
            for (int fa = 0; fa < 4; ++fa)
#pragma unroll
                for (int fb = 0; fb < 4; ++fb)
                    acc[fa][fb] = __builtin_amdgcn_mfma_f32_16x16x32_bf16(
                        wf[fa], hf[fb], acc[fa][fb], 0, 0, 0);
        }
    }

    __hip_bfloat16* Y = Yall + (size_t)n * HWT * 1024;
#pragma unroll
    for (int fa = 0; fa < 4; ++fa)
#pragma unroll
        for (int fb = 0; fb < 4; ++fb) {
            int m = m0 + wm * 64 + fb * 16 + fr;          // D col = lane&15
            int o = o0 + wo * 64 + fa * 16 + kg * 4;      // D row = (lane>>4)*4 + j
            if (m < HWT) {
                f32x4 v = acc[fa][fb];
                union { ushort4 u; __hip_bfloat16 h[4]; } pk;
                pk.h[0] = __float2bfloat16(v.x);
                pk.h[1] = __float2bfloat16(v.y);
                pk.h[2] = __float2bfloat16(v.z);
                pk.h[3] = __float2bfloat16(v.w);
                *(ushort4*)(Y + (size_t)m * 1024 + o) = pk.u;
            }
        }
}

// ---------------- gather / SE / final (unchanged) ----------------
__global__ void zero_cc(float* __restrict__ ccsum) {
    int t = blockIdx.x * blockDim.x + threadIdx.x;
    if (t < NB * 512) ccsum[t] = 0.f;
}

__global__ __launch_bounds__(256) void gather_kernel(const __hip_bfloat16* __restrict__ Yall,
                                                     const int* __restrict__ knn_rgb,
                                                     const int* __restrict__ knn_ir,
                                                     const float* __restrict__ b_rgb,
                                                     const float* __restrict__ b_ir,
                                                     float* __restrict__ ccsum) {
    int n = blockIdx.y;
    int hwbase = blockIdx.x * POSB;
    int c = threadIdx.x;
    __shared__ int sidx[POSB][2][KNN];
    if (c < POSB * 2 * KNN) {
        int p = c >> 4, rem = c & 15;
        int hw = hwbase + p;
        int v;
        if (rem < 8) v = knn_rgb[((size_t)n * HWT + hw) * KNN + rem];
        else         v = knn_ir[((size_t)n * HWT + hw) * KNN + (rem - 8)];
        sidx[p][rem >> 3][rem & 7] = v;
    }
    __syncthreads();
    float br = b_rgb[c], bi = b_ir[c];
    float acc_r = 0.f, acc_i = 0.f;
    const __hip_bfloat16* Y = Yall + (size_t)n * HWT * 1024;
    for (int p = 0; p < POSB; ++p) {
        float mr = 0.f, mi = 0.f;
#pragma unroll
        for (int k = 0; k < KNN; ++k) {
            int jr = sidx[p][0][k];
            int ji = sidx[p][1][k];
            float y1 = __bfloat162float(Y[(size_t)jr * 1024 + c]);
            float y2 = __bfloat162float(Y[(size_t)ji * 1024 + 256 + c]);
            mr = fmaxf(mr, y1 - y2 + br);
            float z1 = __bfloat162float(Y[(size_t)ji * 1024 + 512 + c]);
            float z2 = __bfloat162float(Y[(size_t)jr * 1024 + 768 + c]);
            mi = fmaxf(mi, z1 - z2 + bi);
        }
        acc_r += mr;
        acc_i += mi;
    }
    atomicAdd(&ccsum[n * 512 + c], acc_r);
    atomicAdd(&ccsum[n * 512 + 256 + c], acc_i);
}

__global__ __launch_bounds__(256) void se_kernel(const float* __restrict__ ccsum,
                                                 const float* __restrict__ W1,
                                                 const float* __restrict__ b1,
                                                 const float* __restrict__ W2,
                                                 const float* __restrict__ b2,
                                                 float* __restrict__ g) {
    int n = blockIdx.x;
    int t = threadIdx.x;
    __shared__ float hid[16];
    __shared__ float cc[512];
    cc[t] = ccsum[n * 512 + t] * (1.0f / HWT);
    cc[256 + t] = ccsum[n * 512 + 256 + t] * (1.0f / HWT);
    __syncthreads();
    if (t < 16) {
        float s = b1[t];
        for (int j = 0; j < 512; ++j) s = fmaf(W1[t * 512 + j], cc[j], s);
        hid[t] = fmaxf(s, 0.f);
    }
    __syncthreads();
    float s = b2[t];
#pragma unroll
    for (int q = 0; q < 16; ++q) s = fmaf(W2[t * 16 + q], hid[q], s);
    float se = 1.0f / (1.0f + expf(-s));
    g[n * CH + t] *= se;
}

__global__ void final_kernel(const float* __restrict__ cnn, const float* __restrict__ g,
                             const float* __restrict__ gamma, float* __restrict__ out) {
    int t = blockIdx.x * blockDim.x + threadIdx.x;
    if (t >= NB * CH * HWT) return;
    int nc = t / HWT;
    float x = cnn[t];
    float s = gamma[0] * g[nc] + 1.0f;
    out[t] = fmaxf(s * x, 0.f);
}

extern "C" void kernel_launch(void* const* d_in, const int* in_sizes, int n_in,
                              void* d_out, int out_size, void* d_ws, size_t ws_size,
                              hipStream_t stream) {
    const float* cnn    = (const float*)d_in[0];
    const float* rgb    = (const float*)d_in[1];
    const float* ir     = (const float*)d_in[2];
    const float* Wg_rgb = (const float*)d_in[3];
    const float* bg_rgb = (const float*)d_in[4];
    const float* Wg_ir  = (const float*)d_in[5];
    const float* bg_ir  = (const float*)d_in[6];
    const float* Wse1   = (const float*)d_in[7];
    const float* bse1   = (const float*)d_in[8];
    const float* Wse2   = (const float*)d_in[9];
    const float* bse2   = (const float*)d_in[10];
    const float* gamma  = (const float*)d_in[11];
    float* out = (float*)d_out;

    char* ws = (char*)d_ws;
    size_t off = 0;
    float* xpack = (float*)(ws + off); off += (size_t)2 * NB * HWT * 8 * 4;
    int* knn_rgb = (int*)(ws + off); off += (size_t)NB * HWT * KNN * 4;
    int* knn_ir  = (int*)(ws + off); off += (size_t)NB * HWT * KNN * 4;
    float* Wcomb = (float*)(ws + off); off += (size_t)1024 * 256 * 4;
    __hip_bfloat16* Wbf = (__hip_bfloat16*)(ws + off); off += (size_t)NB * 1024 * CH * 2;
    __hip_bfloat16* Abf = (__hip_bfloat16*)(ws + off); off += (size_t)NB * MPAD * CH * 2;
    __hip_bfloat16* Yall = (__hip_bfloat16*)(ws + off);
    unsigned* partial = (unsigned*)Yall;  // aliases Y: dead before first gemm
    off += (size_t)NB * HWT * 1024 * 2;
    float* ccsum = (float*)(ws + off); off += (size_t)NB * 512 * 4;
    float* g     = (float*)(ws + off); off += (size_t)NB * CH * 4;

    knn_prep<<<(2 * NB * HWT + 255) / 256, 256, 0, stream>>>(rgb, ir, xpack);
    knn_main<<<dim3(S_SEG, 4, 2 * NB), 256, 0, stream>>>(xpack, partial);
    knn_merge<<<(2 * NB * HWT + 255) / 256, 256, 0, stream>>>(partial, knn_rgb, knn_ir);
    init_kernel<<<1024, 256, 0, stream>>>(Wg_rgb, Wg_ir, Wcomb, g);
    convert_a<<<dim3(MPAD / 64, 4, NB), 256, 0, stream>>>(cnn, Abf);

    for (int it = 0; it < ITERS; ++it) {
        scale_w<<<dim3(128, NB), 256, 0, stream>>>(Wcomb, g, Wbf);
        gemm_mfma<<<dim3(MPAD / 128, 8, NB), 256, 0, stream>>>(Abf, Wbf, Yall);
        zero_cc<<<8, 256, 0, stream>>>(ccsum);
        gather_kernel<<<dim3(HWT / POSB, NB), 256, 0, stream>>>(Yall, knn_rgb, knn_ir,
                                                                bg_rgb, bg_ir, ccsum);
        se_kernel<<<NB, 256, 0, stream>>>(ccsum, Wse1, bse1, Wse2, bse2, g);
    }
    final_kernel<<<(NB * CH * HWT + 255) / 256, 256, 0, stream>>>(cnn, g, gamma, out);
}